// Round 8
// baseline (435.554 us; speedup 1.0000x reference)
//
#include <hip/hip_runtime.h>
#include <stdint.h>
#include <math.h>

#define M_DIM 8192
#define N_DIM 4096
#define K_DIM 4096
#define BITWIDTH 7

#define BM 256
#define BN 128
#define BK 128   // bytes of K per tile (row stride in LDS for B)
#define NT (K_DIM / BK)   // 32 K-tiles

using i32x4  = __attribute__((ext_vector_type(4)))  int;
using i32x16 = __attribute__((ext_vector_type(16))) int;

#define FENCE asm volatile("" ::: "memory")

// ---------------------------------------------------------------------------
// Combined pack, one launch:
//   blocks [0, 8192):    A -> MFMA-fragment-blocked int8 layout
//   blocks [8192,16384): B -> row-major int8 (unchanged path)
//
// A packed layout (R4-verified): for M-block mb (32 rows), K-block kb
// (32 bytes), a 1 KB block at ((mb*128 + kb) * 1024); lane L's 16 fragment
// bytes at offset L*16: A[mb*32 + (L&31)][kb*32 + (L>>5)*16 + 0..15].
// ---------------------------------------------------------------------------
__global__ __launch_bounds__(256) void pack_both_kernel(
        const int* __restrict__ act, const int* __restrict__ wt,
        uint32_t* __restrict__ a8p, uint32_t* __restrict__ w8,
        int* __restrict__ maxabs) {
    if (blockIdx.x == 0 && threadIdx.x == 0) *maxabs = 0;

    if (blockIdx.x < 8192) {
        // ---- A fragment pack: 2,097,152 threads, 16B out each ----
        const int tid = blockIdx.x * 256 + threadIdx.x;
        const int L  = tid & 63;
        const int kb = (tid >> 6) & 127;          // K/32 = 128 blocks
        const int mb = tid >> 13;                 // M/32 = 256 blocks
        const size_t src = (size_t)(mb * 32 + (L & 31)) * K_DIM
                         + kb * 32 + (L >> 5) * 16;
        const int4* s = (const int4*)(act + src);
        uint32_t w[4];
#pragma unroll
        for (int q = 0; q < 4; ++q) {
            int4 v = s[q];
            w[q] = (uint32_t)(v.x & 0xFF) | ((uint32_t)(v.y & 0xFF) << 8)
                 | ((uint32_t)(v.z & 0xFF) << 16) | ((uint32_t)(v.w & 0xFF) << 24);
        }
        ((uint4*)a8p)[tid] = make_uint4(w[0], w[1], w[2], w[3]);
    } else {
        // ---- B row-major pack: 8 int32 -> 8 bytes per thread ----
        const int i = (blockIdx.x - 8192) * 256 + threadIdx.x;
        int4 a = ((const int4*)wt)[2 * i];
        int4 b = ((const int4*)wt)[2 * i + 1];
        uint32_t p0 = (uint32_t)(a.x & 0xFF) | ((uint32_t)(a.y & 0xFF) << 8)
                    | ((uint32_t)(a.z & 0xFF) << 16) | ((uint32_t)(a.w & 0xFF) << 24);
        uint32_t p1 = (uint32_t)(b.x & 0xFF) | ((uint32_t)(b.y & 0xFF) << 8)
                    | ((uint32_t)(b.z & 0xFF) << 16) | ((uint32_t)(b.w & 0xFF) << 24);
        ((uint2*)w8)[i] = make_uint2(p0, p1);
    }
}

// ---------------------------------------------------------------------------
// async global->LDS, 16B per lane, LDS dest = wave-uniform base + lane*16
// ---------------------------------------------------------------------------
__device__ __forceinline__ void gload_lds16(const int8_t* g, int8_t* lds) {
    __builtin_amdgcn_global_load_lds(
        (__attribute__((address_space(1))) void*)g,
        (__attribute__((address_space(3))) void*)lds,
        16, 0, 0);
}

// load one kk-step's 2 A fragments (coalesced dwordx4 from packed layout)
__device__ __forceinline__ void load_af(i32x4 (&d)[2], const int8_t* aBase,
                                        int tkk) {
#pragma unroll
    for (int i = 0; i < 2; ++i)
        d[i] = *(const i32x4*)(aBase + (size_t)((i * 128 + tkk) << 10));
}

// load one kk-step's 4 B fragments from LDS (swizzled chunk offset co)
__device__ __forceinline__ void load_bf(i32x4 (&d)[4], const int8_t* bbuf,
                                        const int (&ro)[4], int co) {
#pragma unroll
    for (int j = 0; j < 4; ++j)
        d[j] = *(const i32x4*)(bbuf + ro[j] + co);
}

// one kk-step: 8 MFMAs, all operands pre-loaded (no memory ops inside)
__device__ __forceinline__ void kkstep(const i32x4 (&a)[2], const i32x4 (&b)[4],
                                       i32x16 (&acc)[2][4]) {
#pragma unroll
    for (int i = 0; i < 2; ++i)
#pragma unroll
        for (int j = 0; j < 4; ++j)
            acc[i][j] = __builtin_amdgcn_mfma_i32_32x32x32_i8(
                a[i], b[j], acc[i][j], 0, 0, 0);
}

// ---------------------------------------------------------------------------
// i8 GEMM, R8: 4-phase barrier-aligned schedule (T3+T4+T5 port) on the
// R6-verified geometry (4Mx1N waves, wave tile 64x128, A from frag-packed
// global, B LDS 2-ring with XOR swizzle).
//
// Phase kk (one per 32B k-step):
//   { 4x ds_read bf(kk) | 2x global af(kk+1) | kk==0: 4x gload_lds B(t+1) }
//   s_barrier; lgkmcnt(0); setprio(1); 8 MFMA; setprio(0); s_barrier
// Counted vmcnt(2) only at phase 3 (never 0 in-loop). In-order audit:
// staging (ph0, after af(t,1)) is retired by the compiler's af(t,2) wait
// at ph2 -> ~2 phases (~1200cyc) of HBM cover; af(t+1,0) survives the
// tile-end barrier under vmcnt(2). Buffer flip safe: all reads of the
// staged-over buffer are lgkm-drained before the trailing barrier that
// precedes the staging issues.
// ---------------------------------------------------------------------------
__global__ __launch_bounds__(256, 2) void gemm_i8(
        const int8_t* __restrict__ A8p, const int8_t* __restrict__ B8,
        int* __restrict__ C, int* __restrict__ maxabs) {
    __shared__ __align__(16) int8_t Bs[2][BN * BK];   // 2 x 16 KB ring
    __shared__ int wmaxs[4];
    int8_t* BsF = &Bs[0][0];

    const int tid  = threadIdx.x;
    const int wave = tid >> 6;
    const int lane = tid & 63;
    const int fr   = lane & 31;
    const int hl   = lane >> 5;

    const int row0 = blockIdx.y * BM;
    const int col0 = blockIdx.x * BN;

    const int wm = wave * 64;          // wave row offset (4M x 1N grid)

    i32x16 acc[2][4];
#pragma unroll
    for (int i = 0; i < 2; ++i)
#pragma unroll
        for (int j = 0; j < 4; ++j)
            acc[i][j] = (i32x16)(0);

    // --- B staging addressing (R0-verified) ---------------------------------
    const int srowoff = lane >> 3;
    const int schk    = ((lane & 7) ^ srowoff) << 4;
    const int8_t* bg  = B8 + (size_t)(col0 + wave * 8 + srowoff) * K_DIM + schk;
    const int ldsoB   = wave * 1024;

    // --- A fragment addressing (packed global, coalesced, deduped) ----------
    const int mbase = (row0 >> 5) + wave * 2;
    const int8_t* aBase = A8p + ((size_t)mbase << 17) + (size_t)lane * 16;

    // --- B fragment LDS offsets -------------------------------------------
    const int swz = fr & 7;
    int rowOff[4];
#pragma unroll
    for (int j = 0; j < 4; ++j)
        rowOff[j] = (j * 32 + fr) * BK;
    int co[4];
#pragma unroll
    for (int kk = 0; kk < 4; ++kk)
        co[kk] = ((kk * 2 + hl) ^ swz) << 4;

    i32x4 afE[2], afO[2], bfP[4];

    // --- prologue: stage B(0) into buf 0; prefetch af(0,0) ------------------
#pragma unroll
    for (int g = 0; g < 4; ++g)
        gload_lds16(bg + (size_t)(32 * g) * K_DIM, BsF + ldsoB + g * 4096);
    FENCE;
    load_af(afE, aBase, 0);
    asm volatile("s_waitcnt vmcnt(2)" ::: "memory");   // B(0) landed; afE flying
    __builtin_amdgcn_s_barrier();

    // --- main K loop: 4 barrier-aligned phases per tile ---------------------
    for (int t = 0; t < NT; ++t) {
        const int8_t* bbuf = BsF + ((t & 1) << 14);
        int8_t* bstg = BsF + (((t + 1) & 1) << 14) + ldsoB;
        const bool st = (t < NT - 1);
        const int kg = (t + 1) * BK;

        // ---- phase 0: consume afE(kk0); prefetch afO(kk1); stage B(t+1) ---
        load_bf(bfP, bbuf, rowOff, co[0]); FENCE;
        load_af(afO, aBase, t * 4 + 1);    FENCE;
        if (st) {
#pragma unroll
            for (int g = 0; g < 4; ++g)
                gload_lds16(bg + kg + (size_t)(32 * g) * K_DIM, bstg + g * 4096);
        }
        FENCE;
        __builtin_amdgcn_s_barrier();
        asm volatile("s_waitcnt lgkmcnt(0)" ::: "memory");
        __builtin_amdgcn_s_setprio(1);
        kkstep(afE, bfP, acc);
        __builtin_amdgcn_s_setprio(0);
        __builtin_amdgcn_s_barrier();

        // ---- phase 1: consume afO(kk1); prefetch afE(kk2) ------------------
        load_bf(bfP, bbuf, rowOff, co[1]); FENCE;
        load_af(afE, aBase, t * 4 + 2);    FENCE;
        __builtin_amdgcn_s_barrier();
        asm volatile("s_waitcnt lgkmcnt(0)" ::: "memory");
        __builtin_amdgcn_s_setprio(1);
        kkstep(afO, bfP, acc);
        __builtin_amdgcn_s_setprio(0);
        __builtin_amdgcn_s_barrier();

        // ---- phase 2: consume afE(kk2); prefetch afO(kk3) ------------------
        load_bf(bfP, bbuf, rowOff, co[2]); FENCE;
        load_af(afO, aBase, t * 4 + 3);    FENCE;
        __builtin_amdgcn_s_barrier();
        asm volatile("s_waitcnt lgkmcnt(0)" ::: "memory");
        __builtin_amdgcn_s_setprio(1);
        kkstep(afE, bfP, acc);
        __builtin_amdgcn_s_setprio(0);
        __builtin_amdgcn_s_barrier();

        // ---- phase 3: consume afO(kk3); prefetch afE(t+1,kk0); flip --------
        load_bf(bfP, bbuf, rowOff, co[3]); FENCE;
        load_af(afE, aBase, st ? (t * 4 + 4) : 0); FENCE;  // clamped last tile
        __builtin_amdgcn_s_barrier();
        asm volatile("s_waitcnt lgkmcnt(0)" ::: "memory");
        __builtin_amdgcn_s_setprio(1);
        kkstep(afO, bfP, acc);
        __builtin_amdgcn_s_setprio(0);
        asm volatile("s_waitcnt vmcnt(2)" ::: "memory");   // staging retired
        __builtin_amdgcn_s_barrier();
    }

    // epilogue: 32x32 C/D layout: col = lane&31,
    // row = (reg&3) + 8*(reg>>2) + 4*(lane>>5)   [m74/m101, dtype-independent]
    int mymax = 0;
    const int ccol = fr;
    const int rbase = hl << 2;
#pragma unroll
    for (int i = 0; i < 2; ++i) {
#pragma unroll
        for (int j = 0; j < 4; ++j) {
            int* p = C + (size_t)(row0 + wm + i * 32) * N_DIM
                       + (col0 + j * 32 + ccol);
#pragma unroll
            for (int r = 0; r < 16; ++r) {
                int row = (r & 3) + 8 * (r >> 2) + rbase;
                int v = acc[i][j][r];
                p[(size_t)row * N_DIM] = v;
                int a = v < 0 ? -v : v;
                mymax = a > mymax ? a : mymax;
            }
        }
    }

    // wave-reduce max, then one atomic per block
#pragma unroll
    for (int off = 32; off > 0; off >>= 1) {
        int o = __shfl_down(mymax, off, 64);
        mymax = o > mymax ? o : mymax;
    }
    if (lane == 0) wmaxs[wave] = mymax;
    __syncthreads();
    if (tid == 0) {
        int bmx = wmaxs[0];
        for (int w = 1; w < 4; ++w) bmx = wmaxs[w] > bmx ? wmaxs[w] : bmx;
        atomicMax(maxabs, bmx);
    }
}

// ---------------------------------------------------------------------------
// Pseudo-stochastic shift, faithful to PstoShiftInt32 (all-integer, exact).
// ---------------------------------------------------------------------------
__device__ __forceinline__ int psto(int x, int eff) {
    if (eff > 0) {
        int rt   = x >> eff;                 // floor divide by 2^eff
        int prob = x & ((1 << eff) - 1);     // non-negative floor remainder
        int h    = eff >> 1;
        int qp   = prob >> h;
        int prn  = (prob & ((1 << h) - 1)) << (eff & 1);
        int sgn  = (x > 0) - (x < 0);
        int r    = rt + ((qp <= prn) ? 0 : sgn);
        r = r < -127 ? -127 : r;
        r = r > 127 ? 127 : r;
        return r;
    }
    return (int)(int8_t)x;                   // wrapping int8 cast, as in torch
}

// ---------------------------------------------------------------------------
// In-place: read int32 acc from C, write int32 quantized value back.
// ---------------------------------------------------------------------------
__global__ __launch_bounds__(256) void finalize_kernel(int* __restrict__ C,
        const int* __restrict__ maxabs,
        const int* __restrict__ exp_in,
        const int* __restrict__ wexp) {
    const int m = *maxabs;
    int bw = 0;
    if (m != 0) bw = (int)ceilf(log2f((float)m));   // float32 path, as reference
    const int shift = bw - BITWIDTH;
    const int eff = (shift > 1) ? shift : ((shift == 1) ? 2 : 0);

    const size_t idx = ((size_t)blockIdx.x * blockDim.x + threadIdx.x) * 8;
    int4 v0 = *(const int4*)(C + idx);
    int4 v1 = *(const int4*)(C + idx + 4);
    int4 o0, o1;
    o0.x = psto(v0.x, eff); o0.y = psto(v0.y, eff);
    o0.z = psto(v0.z, eff); o0.w = psto(v0.w, eff);
    o1.x = psto(v1.x, eff); o1.y = psto(v1.y, eff);
    o1.z = psto(v1.z, eff); o1.w = psto(v1.w, eff);
    *(int4*)(C + idx) = o0;
    *(int4*)(C + idx + 4) = o1;

    if (idx == 0) {
        C[(size_t)M_DIM * N_DIM] = (int)(int8_t)(exp_in[0] + wexp[0] + eff);
    }
}

// ---------------------------------------------------------------------------
extern "C" void kernel_launch(void* const* d_in, const int* in_sizes, int n_in,
                              void* d_out, int out_size, void* d_ws, size_t ws_size,
                              hipStream_t stream) {
    const int* act    = (const int*)d_in[0];
    const int* exp_in = (const int*)d_in[1];
    const int* wt     = (const int*)d_in[2];
    const int* wexp   = (const int*)d_in[3];

    int8_t* a8p    = (int8_t*)d_ws;                          // 32 MB (frag-packed)
    int8_t* w8     = a8p + (size_t)M_DIM * K_DIM;            // 16 MB
    int*    maxabs = (int*)(w8 + (size_t)N_DIM * K_DIM);     // 4 B

    // blocks [0,8192): A frag-pack; [8192,16384): B row-major pack
    pack_both_kernel<<<16384, 256, 0, stream>>>(
        act, wt, (uint32_t*)a8p, (uint32_t*)w8, maxabs);

    int* C = (int*)d_out;    // acc staged in-place in d_out
    dim3 grid(N_DIM / BN, M_DIM / BM);
    gemm_i8<<<grid, 256, 0, stream>>>(a8p, w8, C, maxabs);

    finalize_kernel<<<((size_t)M_DIM * N_DIM / 8) / 256, 256, 0, stream>>>(
        C, maxabs, exp_in, wexp);
}